// Round 3
// baseline (372.836 us; speedup 1.0000x reference)
//
#include <hip/hip_runtime.h>
#include <hip/hip_bf16.h>

typedef __hip_bfloat16 bf16;
typedef float f32x4 __attribute__((ext_vector_type(4)));
typedef short s16x8 __attribute__((ext_vector_type(8)));

// ---------------------------------------------------------------------------
__device__ __forceinline__ void async_load16(const void* g, void* lds) {
  __builtin_amdgcn_global_load_lds(
      (const __attribute__((address_space(1))) void*)g,
      (__attribute__((address_space(3))) void*)lds, 16, 0, 0);
}

#define WAITV(N) asm volatile("s_waitcnt vmcnt(" #N ")" ::: "memory")

__device__ __forceinline__ void wg_barrier() {
  __builtin_amdgcn_s_barrier();
  asm volatile("" ::: "memory");
}

__device__ __forceinline__ f32x4 MFMA(s16x8 a, s16x8 b, f32x4 c) {
  return __builtin_amdgcn_mfma_f32_16x16x32_bf16(a, b, c, 0, 0, 0);
}

__device__ __forceinline__ void store_out(float* p, float v) { *p = v; }
__device__ __forceinline__ void store_out(bf16* p, float v) { *p = __float2bfloat16(v); }

// ---------------------------------------------------------------------------
// 256x256 tile GEMM, BK=64, 8 waves (2x4), 4-phase K-loop with half-granular
// (k-split) 1.5-tile prefetch, counted vmcnt(8), raw barriers, setprio.
// C[M,N] = scale*(A[M,K] @ BT[N,K]^T) + bias.
//
// LDS: As/Bs[buf][kh][256*32], kh = 32-wide K half. 128 KiB total.
// Issue order (per thread, 2 gload_lds each; ledger for vmcnt counts):
//   prologue: Ak0(0) Bk0(0) Ak1(0) Bk1(0) Ak0(1) Bk0(1)    -> WAITV(8)
//   tile t ph0: Ak1(t+1)   ph1: Bk1(t+1)  [-> WAITV(8): Ak1/Bk1(t) landed]
//          ph2: Ak0(t+2)   ph3: Bk0(t+2)  [-> WAITV(8): Ak0/Bk0(t+1) landed]
// Region overwrite safety: each stage targets a region whose last reader
// finished >=1 barrier before the issuing point (verified per phase).
template <typename OutT, bool BIAS, int SWZ>
__global__ __launch_bounds__(512, 2)
void gemm256(const bf16* __restrict__ Ag, const bf16* __restrict__ Bg,
             OutT* Cg, const float* __restrict__ biasp, float scale,
             int K, int lda, int ldb, int ldc, int ntx,
             long long sA, long long sB, long long sC) {
  __shared__ bf16 As[2][2][256 * 32];
  __shared__ bf16 Bs[2][2][256 * 32];

  const int id = blockIdx.x;
  int bz = 0, tile;
  if (SWZ == 1) { bz = id & 7; tile = id >> 3; }          // batch -> XCD pin
  else if (SWZ == 2) { const int q = gridDim.x >> 3; tile = (id & 7) * q + (id >> 3); }
  else tile = id;
  const int tn = tile % ntx, tm = tile / ntx;

  const bf16* A = Ag + bz * sA + (long long)tm * 256 * lda;
  const bf16* BT = Bg + bz * sB + (long long)tn * 256 * ldb;
  OutT* C = Cg + bz * sC;

  const int t = threadIdx.x;
  const int lane = t & 63, wid = t >> 6;
  const int wr = wid >> 2, wc = wid & 3;          // 2 (M) x 4 (N) waves
  const int lo = lane & 15, hi = lane >> 4, hi8 = hi * 8;

  const int sr = t >> 2, sc = (t & 3) * 8;        // staging row / col(elem)
  const int NT = K >> 6;                          // K-tiles of 64 (NT >= 2)

  f32x4 acc[8][4] = {};

  auto stage = [&](const bf16* gp, int ld, bf16* region) {
    async_load16(gp + (long long)sr * ld + sc, region + t * 8);
    async_load16(gp + (long long)(sr + 128) * ld + sc, region + (t + 512) * 8);
  };

  // ---- prologue (order matters for vmcnt ledger)
  stage(A, lda, &As[0][0][0]);          // Ak0(0)
  stage(BT, ldb, &Bs[0][0][0]);         // Bk0(0)
  stage(A + 32, lda, &As[0][1][0]);     // Ak1(0)
  stage(BT + 32, ldb, &Bs[0][1][0]);    // Bk1(0)
  stage(A + 64, lda, &As[1][0][0]);     // Ak0(1)
  stage(BT + 64, ldb, &Bs[1][0][0]);    // Bk0(1)
  WAITV(8);                             // Ak0(0),Bk0(0) landed
  wg_barrier();

  const int arow = wr * 128 + lo;
  const int brow = wc * 64 + lo;

  for (int kt = 0; kt < NT; ++kt) {
    const int c = kt & 1;
    const bool i1 = kt + 1 < NT, i2 = kt + 2 < NT;
    const bf16* Ar0 = &As[c][0][0];
    const bf16* Br0 = &Bs[c][0][0];
    const bf16* Ar1 = &As[c][1][0];
    const bf16* Br1 = &Bs[c][1][0];
    s16x8 a[8], b0, b1, b2, b3;

    // ---- phase 0: kh0 x n{0,1}
    if (i1) stage(A + (kt + 1) * 64 + 32, lda, &As[c ^ 1][1][0]);   // Ak1(t+1)
#pragma unroll
    for (int m = 0; m < 8; ++m)
      a[m] = *(const s16x8*)&Ar0[(arow + m * 16) * 32 + hi8];
    b0 = *(const s16x8*)&Br0[(brow) * 32 + hi8];
    b1 = *(const s16x8*)&Br0[(brow + 16) * 32 + hi8];
    __builtin_amdgcn_s_setprio(1);
#pragma unroll
    for (int m = 0; m < 8; ++m) {
      acc[m][0] = MFMA(a[m], b0, acc[m][0]);
      acc[m][1] = MFMA(a[m], b1, acc[m][1]);
    }
    __builtin_amdgcn_s_setprio(0);
    wg_barrier();

    // ---- phase 1: kh0 x n{2,3} (reuse a[])
    if (i1) stage(BT + (kt + 1) * 64 + 32, ldb, &Bs[c ^ 1][1][0]);  // Bk1(t+1)
    b2 = *(const s16x8*)&Br0[(brow + 32) * 32 + hi8];
    b3 = *(const s16x8*)&Br0[(brow + 48) * 32 + hi8];
    __builtin_amdgcn_s_setprio(1);
#pragma unroll
    for (int m = 0; m < 8; ++m) {
      acc[m][2] = MFMA(a[m], b2, acc[m][2]);
      acc[m][3] = MFMA(a[m], b3, acc[m][3]);
    }
    __builtin_amdgcn_s_setprio(0);
    if (i1) { WAITV(8); } else { WAITV(0); }   // guard Ak1(t),Bk1(t)
    wg_barrier();

    // ---- phase 2: kh1 x n{0,1}
    if (i2) stage(A + (kt + 2) * 64, lda, &As[c][0][0]);            // Ak0(t+2)
#pragma unroll
    for (int m = 0; m < 8; ++m)
      a[m] = *(const s16x8*)&Ar1[(arow + m * 16) * 32 + hi8];
    b0 = *(const s16x8*)&Br1[(brow) * 32 + hi8];
    b1 = *(const s16x8*)&Br1[(brow + 16) * 32 + hi8];
    __builtin_amdgcn_s_setprio(1);
#pragma unroll
    for (int m = 0; m < 8; ++m) {
      acc[m][0] = MFMA(a[m], b0, acc[m][0]);
      acc[m][1] = MFMA(a[m], b1, acc[m][1]);
    }
    __builtin_amdgcn_s_setprio(0);
    wg_barrier();

    // ---- phase 3: kh1 x n{2,3}
    if (i2) stage(BT + (kt + 2) * 64, ldb, &Bs[c][0][0]);           // Bk0(t+2)
    b2 = *(const s16x8*)&Br1[(brow + 32) * 32 + hi8];
    b3 = *(const s16x8*)&Br1[(brow + 48) * 32 + hi8];
    __builtin_amdgcn_s_setprio(1);
#pragma unroll
    for (int m = 0; m < 8; ++m) {
      acc[m][2] = MFMA(a[m], b2, acc[m][2]);
      acc[m][3] = MFMA(a[m], b3, acc[m][3]);
    }
    __builtin_amdgcn_s_setprio(0);
    if (i2) { WAITV(8); } else if (i1) { WAITV(4); }  // guard Ak0/Bk0(t+1)
    wg_barrier();
  }

  // ---- epilogue
#pragma unroll
  for (int n = 0; n < 4; ++n) {
    const int col = tn * 256 + wc * 64 + n * 16 + lo;
    float bv = 0.f;
    if (BIAS) bv = biasp[col];
#pragma unroll
    for (int m = 0; m < 8; ++m) {
      const int row = tm * 256 + wr * 128 + m * 16 + hi * 4;
#pragma unroll
      for (int j = 0; j < 4; ++j)
        store_out(&C[(long long)(row + j) * ldc + col], acc[m][n][j] * scale + bv);
    }
  }
}

// ---------------------------------------------------------------------------
__global__ void cvt_f32_bf16(const float* __restrict__ in, bf16* __restrict__ out,
                             long long n4) {
  long long i = (long long)blockIdx.x * 256 + threadIdx.x;
  if (i >= n4) return;
  float4 v = reinterpret_cast<const float4*>(in)[i];
  union { bf16 h[4]; unsigned long long u; } cv;
  cv.h[0] = __float2bfloat16(v.x);
  cv.h[1] = __float2bfloat16(v.y);
  cv.h[2] = __float2bfloat16(v.z);
  cv.h[3] = __float2bfloat16(v.w);
  reinterpret_cast<unsigned long long*>(out)[i] = cv.u;
}

__global__ void transpose_f32_to_bf16(const float* __restrict__ in, bf16* __restrict__ out,
                                      int R, int C) {
  __shared__ float tile[32][33];
  const int bx = blockIdx.x * 32, by = blockIdx.y * 32;
  const int tx = threadIdx.x & 31, ty = threadIdx.x >> 5;
#pragma unroll
  for (int i = 0; i < 32; i += 8)
    tile[ty + i][tx] = in[(long long)(by + ty + i) * C + bx + tx];
  __syncthreads();
#pragma unroll
  for (int i = 0; i < 32; i += 8)
    out[(long long)(bx + ty + i) * R + by + tx] = __float2bfloat16(tile[tx][ty + i]);
}

__global__ void transpose_bf16_b(const bf16* __restrict__ in, bf16* __restrict__ out,
                                 int ld_in, int ld_out, long long sIn, long long sOut) {
  __shared__ bf16 tile[32][33];
  const bf16* ip = in + blockIdx.z * sIn;
  bf16* op = out + blockIdx.z * sOut;
  const int bx = blockIdx.x * 32;
  const int by = blockIdx.y * 32;
  const int tx = threadIdx.x & 31, ty = threadIdx.x >> 5;
#pragma unroll
  for (int i = 0; i < 32; i += 8)
    tile[ty + i][tx] = ip[(long long)(by + ty + i) * ld_in + bx + tx];
  __syncthreads();
#pragma unroll
  for (int i = 0; i < 32; i += 8)
    op[(long long)(bx + ty + i) * ld_out + by + tx] = tile[tx][ty + i];
}

__global__ void concat_bias(const float* __restrict__ a, const float* __restrict__ b,
                            float* __restrict__ out) {
  int i = blockIdx.x * 256 + threadIdx.x;
  out[i] = (i < 1024) ? a[i] : b[i - 1024];
}

// ---------------------------------------------------------------------------
__global__ void softmax_mask(bf16* __restrict__ S, const int* __restrict__ mask) {
  const int row = blockIdx.x;
  const int b = row >> 10;
  bf16* s = S + (long long)row * 2048;
  const int* mk = mask + b * 2048;
  const int t = threadIdx.x;
  const int lane = t & 63, wid = t >> 6;

  s16x8 xv = reinterpret_cast<const s16x8*>(s)[t];
  int4 m0 = reinterpret_cast<const int4*>(mk)[t * 2];
  int4 m1 = reinterpret_cast<const int4*>(mk)[t * 2 + 1];

  union { s16x8 v; bf16 h[8]; } u;
  u.v = xv;
  float v[8];
  const int mm[8] = {m0.x, m0.y, m0.z, m0.w, m1.x, m1.y, m1.z, m1.w};
#pragma unroll
  for (int j = 0; j < 8; ++j) v[j] = mm[j] ? __bfloat162float(u.h[j]) : -INFINITY;

  float mx = v[0];
#pragma unroll
  for (int j = 1; j < 8; ++j) mx = fmaxf(mx, v[j]);
  for (int off = 32; off; off >>= 1) mx = fmaxf(mx, __shfl_xor(mx, off, 64));
  __shared__ float redm[4];
  if (lane == 0) redm[wid] = mx;
  __syncthreads();
  mx = fmaxf(fmaxf(redm[0], redm[1]), fmaxf(redm[2], redm[3]));

  float e[8], sum = 0.f;
#pragma unroll
  for (int j = 0; j < 8; ++j) { e[j] = __expf(v[j] - mx); sum += e[j]; }
  for (int off = 32; off; off >>= 1) sum += __shfl_xor(sum, off, 64);
  __shared__ float reds[4];
  if (lane == 0) reds[wid] = sum;
  __syncthreads();
  sum = reds[0] + reds[1] + reds[2] + reds[3];
  const float inv = 1.0f / sum;

  union { bf16 h[8]; s16x8 v; } o;
#pragma unroll
  for (int j = 0; j < 8; ++j) o.h[j] = __float2bfloat16(e[j] * inv);
  reinterpret_cast<s16x8*>(s)[t] = o.v;
}

// ---------------------------------------------------------------------------
extern "C" void kernel_launch(void* const* d_in, const int* in_sizes, int n_in,
                              void* d_out, int out_size, void* d_ws, size_t ws_size,
                              hipStream_t stream) {
  const float* query = (const float*)d_in[0];      // [8,1024,1024]
  const float* key_value = (const float*)d_in[1];  // [8,2048,1024]
  const int* key_mask = (const int*)d_in[2];       // [8,2048]
  const float* Wq = (const float*)d_in[3];
  const float* bq = (const float*)d_in[4];
  const float* Wk = (const float*)d_in[5];
  const float* bk = (const float*)d_in[6];
  const float* Wv = (const float*)d_in[7];
  const float* bv = (const float*)d_in[8];
  const float* Wo = (const float*)d_in[9];
  const float* bo = (const float*)d_in[10];
  float* out = (float*)d_out;

  char* ws = (char*)d_ws;
  size_t off = 0;
  auto alloc = [&](size_t bytes) {
    char* p = ws + off;
    off += (bytes + 255) & ~(size_t)255;
    return p;
  };
  bf16* qb   = (bf16*)alloc(8192ull * 1024 * 2);
  bf16* kvb  = (bf16*)alloc(16384ull * 1024 * 2);
  bf16* WqT  = (bf16*)alloc(1024ull * 1024 * 2);
  bf16* WkvT = (bf16*)alloc(2048ull * 1024 * 2);
  bf16* WoT  = (bf16*)alloc(1024ull * 1024 * 2);
  float* bkv = (float*)alloc(2048 * 4);
  bf16* Qb   = (bf16*)alloc(8192ull * 1024 * 2);
  bf16* KVb  = (bf16*)alloc(16384ull * 2048 * 2);
  bf16* S    = (bf16*)alloc(8ull * 1024 * 2048 * 2);
  bf16* VT = kvb;  // alias: kv bf16 dead after KV projection
  bf16* Cb = Qb;   // alias: Qb dead after scores GEMM

  // 1. conversions / weight prep
  cvt_f32_bf16<<<8192, 256, 0, stream>>>(query, qb, 8192ll * 1024 / 4);
  cvt_f32_bf16<<<16384, 256, 0, stream>>>(key_value, kvb, 16384ll * 1024 / 4);
  transpose_f32_to_bf16<<<dim3(32, 32), 256, 0, stream>>>(Wq, WqT, 1024, 1024);
  transpose_f32_to_bf16<<<dim3(32, 32), 256, 0, stream>>>(Wk, WkvT, 1024, 1024);
  transpose_f32_to_bf16<<<dim3(32, 32), 256, 0, stream>>>(Wv, WkvT + 1024ll * 1024, 1024, 1024);
  transpose_f32_to_bf16<<<dim3(32, 32), 256, 0, stream>>>(Wo, WoT, 1024, 1024);
  concat_bias<<<8, 256, 0, stream>>>(bk, bv, bkv);

  // 2. Q projection: [8192,1024] -> Qb
  gemm256<bf16, true, 2><<<128, 512, 0, stream>>>(
      qb, WqT, Qb, bq, 1.f, 1024, 1024, 1024, 1024, 4, 0, 0, 0);

  // 3. fused K|V projection: [16384,1024] @ [Wk|Wv] -> KVb [16384,2048]
  gemm256<bf16, true, 2><<<512, 512, 0, stream>>>(
      kvb, WkvT, KVb, bkv, 1.f, 1024, 1024, 1024, 2048, 8, 0, 0, 0);

  // 4. V^T per batch
  transpose_bf16_b<<<dim3(32, 64, 8), 256, 0, stream>>>(
      KVb + 1024, VT, 2048, 2048, 2048ll * 2048, 1024ll * 2048);

  // 5. scores: S = (Q @ K^T)/32, bf16
  gemm256<bf16, false, 1><<<256, 512, 0, stream>>>(
      Qb, KVb, S, nullptr, 0.03125f, 1024, 1024, 2048, 2048, 8,
      1024ll * 1024, 2048ll * 2048, 1024ll * 2048);

  // 6. masked softmax in-place
  softmax_mask<<<8192, 256, 0, stream>>>(S, key_mask);

  // 7. context = P @ V
  gemm256<bf16, false, 1><<<128, 512, 0, stream>>>(
      S, VT, Cb, nullptr, 1.f, 2048, 2048, 2048, 1024, 4,
      1024ll * 2048, 1024ll * 2048, 1024ll * 1024);

  // 8. out = Cb @ Wo + bo
  gemm256<float, true, 2><<<128, 512, 0, stream>>>(
      Cb, WoT, out, bo, 1.f, 1024, 1024, 1024, 1024, 4, 0, 0, 0);
}

// Round 4
// 328.233 us; speedup vs baseline: 1.1359x; 1.1359x over previous
//
#include <hip/hip_runtime.h>
#include <hip/hip_bf16.h>

typedef __hip_bfloat16 bf16;
typedef float f32x4 __attribute__((ext_vector_type(4)));
typedef short s16x8 __attribute__((ext_vector_type(8)));

// ---------------------------------------------------------------------------
__device__ __forceinline__ void async_load16(const void* g, void* lds) {
  __builtin_amdgcn_global_load_lds(
      (const __attribute__((address_space(1))) void*)g,
      (__attribute__((address_space(3))) void*)lds, 16, 0, 0);
}

#define WAITV(N) asm volatile("s_waitcnt vmcnt(" #N ")" ::: "memory")

// memory-clobber on BOTH sides: no LDS/global op may cross the barrier
__device__ __forceinline__ void wg_barrier() {
  asm volatile("" ::: "memory");
  __builtin_amdgcn_s_barrier();
  asm volatile("" ::: "memory");
}

__device__ __forceinline__ f32x4 MFMA(s16x8 a, s16x8 b, f32x4 c) {
  return __builtin_amdgcn_mfma_f32_16x16x32_bf16(a, b, c, 0, 0, 0);
}

__device__ __forceinline__ void store_out(float* p, float v) { *p = v; }
__device__ __forceinline__ void store_out(bf16* p, float v) { *p = __float2bfloat16(v); }

// ---------------------------------------------------------------------------
// 256xBN tile GEMM, BK=64, 8 waves, 4-phase K-loop.
// Per phase: {stage prefetch, ds_read fragment set} -> BAR -> MFMA cluster
// -> [WAITV ledger at ph1/ph3] -> BAR.  ds_reads issued PRE-barrier so their
// drain overlaps other waves' MFMA (m201 two-barrier structure).
// LDS regions [R][32] bf16 (R=256 A, R=BN B), K-split halves, dbuf by tile
// parity. Swizzle: phys slot = hi ^ ((row>>1)&3), inverse-applied on the
// global source of global_load_lds (rule 21: both sides or neither).
//
// vmcnt ledger (loads/stage: A=2, B=BN/128; N8=(2+BJ)*2, NH=2+BJ):
//   prologue: A0(0) B0(0) A1(0) B1(0) A0(1) B0(1) -> WAITV(N8)
//   ph0: +A1(t+1)  ph1: +B1(t+1) -> WAITV(N8): A1/B1(t) landed (tail: 0)
//   ph2: +A0(t+2)  ph3: +B0(t+2) -> WAITV(N8): A0/B0(t+1) landed (tail: NH/skip)
// Overwrite safety: stage at ph_p targets a region whose readers all completed
// (lgkm-consumed) before the barrier preceding ph_p. Verified per phase.
template <typename OutT, bool BIAS, int SWZ, int BN>
__global__ __launch_bounds__(512, 2)
void gemm256(const bf16* __restrict__ Ag, const bf16* __restrict__ Bg,
             OutT* Cg, const float* __restrict__ biasp, float scale,
             int K, int lda, int ldb, int ldc, int ntx,
             long long sA, long long sB, long long sC) {
  constexpr int MFR = (BN == 256) ? 8 : 4;   // m frags per wave
  constexpr int WCN = (BN == 256) ? 4 : 2;   // waves along N
  constexpr int BJ = BN / 128;               // B stage chunks per thread
  __shared__ bf16 As[2][2][256 * 32];
  __shared__ bf16 Bs[2][2][BN * 32];

  const int id = blockIdx.x;
  int bz = 0, tile;
  if (SWZ == 1) { bz = id & 7; tile = id >> 3; }          // batch -> XCD pin
  else { const int q = gridDim.x >> 3; tile = (id & 7) * q + (id >> 3); }
  const int tn = tile % ntx, tm = tile / ntx;

  const bf16* A = Ag + bz * sA + (long long)tm * 256 * lda;
  const bf16* BT = Bg + bz * sB + (long long)tn * BN * ldb;
  OutT* C = Cg + bz * sC;

  const int t = threadIdx.x;
  const int lane = t & 63, wid = t >> 6;
  const int wr = wid / WCN, wc = wid % WCN;
  const int lo = lane & 15, hi = lane >> 4;
  const int loff = (hi ^ ((lo >> 1) & 3)) * 8;  // swizzled read slot (elems)

  const int NT = K >> 6;

  // staging lane constants: chunk q=(t+j*512) -> row q>>2, phys slot q&3;
  // fetch global slot (q&3) ^ ((row>>1)&3)
  int srow[2], sgo[2];
#pragma unroll
  for (int j = 0; j < 2; ++j) {
    const int q = t + j * 512;
    const int row = q >> 2;
    srow[j] = row;
    sgo[j] = ((q & 3) ^ ((row >> 1) & 3)) * 8;
  }

  auto stageA = [&](const bf16* gp, bf16* region) {
#pragma unroll
    for (int j = 0; j < 2; ++j)
      async_load16(gp + (long long)srow[j] * lda + sgo[j], region + (t + j * 512) * 8);
  };
  auto stageB = [&](const bf16* gp, bf16* region) {
#pragma unroll
    for (int j = 0; j < BJ; ++j)
      async_load16(gp + (long long)srow[j] * ldb + sgo[j], region + (t + j * 512) * 8);
  };

  f32x4 acc[MFR][4] = {};

  // ---- prologue
  stageA(A, &As[0][0][0]);
  stageB(BT, &Bs[0][0][0]);
  stageA(A + 32, &As[0][1][0]);
  stageB(BT + 32, &Bs[0][1][0]);
  stageA(A + 64, &As[1][0][0]);
  stageB(BT + 64, &Bs[1][0][0]);
  if constexpr (BN == 256) WAITV(8); else WAITV(6);
  wg_barrier();

  const int abase = wr * (MFR * 16) + lo;
  const int bbase = wc * 64 + lo;

  for (int kt = 0; kt < NT; ++kt) {
    const int c = kt & 1;
    const bf16* A0r = &As[c][0][0];
    const bf16* A1r = &As[c][1][0];
    const bf16* B0r = &Bs[c][0][0];
    const bf16* B1r = &Bs[c][1][0];
    s16x8 a[MFR], b0, b1;

    // ---- ph0: kh0 x n{0,1}
    if (kt + 1 < NT) stageA(A + (kt + 1) * 64 + 32, &As[c ^ 1][1][0]);
#pragma unroll
    for (int m = 0; m < MFR; ++m)
      a[m] = *(const s16x8*)&A0r[(abase + m * 16) * 32 + loff];
    b0 = *(const s16x8*)&B0r[bbase * 32 + loff];
    b1 = *(const s16x8*)&B0r[(bbase + 16) * 32 + loff];
    wg_barrier();
    __builtin_amdgcn_sched_barrier(0);
    __builtin_amdgcn_s_setprio(1);
#pragma unroll
    for (int m = 0; m < MFR; ++m) {
      acc[m][0] = MFMA(a[m], b0, acc[m][0]);
      acc[m][1] = MFMA(a[m], b1, acc[m][1]);
    }
    __builtin_amdgcn_s_setprio(0);
    wg_barrier();

    // ---- ph1: kh0 x n{2,3} (reuse a[])
    if (kt + 1 < NT) stageB(BT + (kt + 1) * 64 + 32, &Bs[c ^ 1][1][0]);
    b0 = *(const s16x8*)&B0r[(bbase + 32) * 32 + loff];
    b1 = *(const s16x8*)&B0r[(bbase + 48) * 32 + loff];
    wg_barrier();
    __builtin_amdgcn_sched_barrier(0);
    __builtin_amdgcn_s_setprio(1);
#pragma unroll
    for (int m = 0; m < MFR; ++m) {
      acc[m][2] = MFMA(a[m], b0, acc[m][2]);
      acc[m][3] = MFMA(a[m], b1, acc[m][3]);
    }
    __builtin_amdgcn_s_setprio(0);
    if (kt + 1 < NT) { if constexpr (BN == 256) WAITV(8); else WAITV(6); }
    else WAITV(0);
    wg_barrier();

    // ---- ph2: kh1 x n{0,1}
    if (kt + 2 < NT) stageA(A + (kt + 2) * 64, &As[c][0][0]);
#pragma unroll
    for (int m = 0; m < MFR; ++m)
      a[m] = *(const s16x8*)&A1r[(abase + m * 16) * 32 + loff];
    b0 = *(const s16x8*)&B1r[bbase * 32 + loff];
    b1 = *(const s16x8*)&B1r[(bbase + 16) * 32 + loff];
    wg_barrier();
    __builtin_amdgcn_sched_barrier(0);
    __builtin_amdgcn_s_setprio(1);
#pragma unroll
    for (int m = 0; m < MFR; ++m) {
      acc[m][0] = MFMA(a[m], b0, acc[m][0]);
      acc[m][1] = MFMA(a[m], b1, acc[m][1]);
    }
    __builtin_amdgcn_s_setprio(0);
    wg_barrier();

    // ---- ph3: kh1 x n{2,3}
    if (kt + 2 < NT) stageB(BT + (kt + 2) * 64, &Bs[c][0][0]);
    b0 = *(const s16x8*)&B1r[(bbase + 32) * 32 + loff];
    b1 = *(const s16x8*)&B1r[(bbase + 48) * 32 + loff];
    wg_barrier();
    __builtin_amdgcn_sched_barrier(0);
    __builtin_amdgcn_s_setprio(1);
#pragma unroll
    for (int m = 0; m < MFR; ++m) {
      acc[m][2] = MFMA(a[m], b0, acc[m][2]);
      acc[m][3] = MFMA(a[m], b1, acc[m][3]);
    }
    __builtin_amdgcn_s_setprio(0);
    if (kt + 2 < NT) { if constexpr (BN == 256) WAITV(8); else WAITV(6); }
    else if (kt + 1 < NT) { if constexpr (BN == 256) WAITV(4); else WAITV(3); }
    wg_barrier();
  }

  // ---- epilogue: col = lane&15, row = (lane>>4)*4 + reg
#pragma unroll
  for (int n = 0; n < 4; ++n) {
    const int col = tn * BN + wc * 64 + n * 16 + lo;
    float bv = 0.f;
    if (BIAS) bv = biasp[col];
#pragma unroll
    for (int m = 0; m < MFR; ++m) {
      const int row = tm * 256 + wr * (MFR * 16) + m * 16 + hi * 4;
#pragma unroll
      for (int j = 0; j < 4; ++j)
        store_out(&C[(long long)(row + j) * ldc + col], acc[m][n][j] * scale + bv);
    }
  }
}

// ---------------------------------------------------------------------------
__global__ void cvt_f32_bf16(const float* __restrict__ in, bf16* __restrict__ out,
                             long long n4) {
  long long i = (long long)blockIdx.x * 256 + threadIdx.x;
  if (i >= n4) return;
  float4 v = reinterpret_cast<const float4*>(in)[i];
  union { bf16 h[4]; unsigned long long u; } cv;
  cv.h[0] = __float2bfloat16(v.x);
  cv.h[1] = __float2bfloat16(v.y);
  cv.h[2] = __float2bfloat16(v.z);
  cv.h[3] = __float2bfloat16(v.w);
  reinterpret_cast<unsigned long long*>(out)[i] = cv.u;
}

__global__ void transpose_f32_to_bf16(const float* __restrict__ in, bf16* __restrict__ out,
                                      int R, int C) {
  __shared__ float tile[32][33];
  const int bx = blockIdx.x * 32, by = blockIdx.y * 32;
  const int tx = threadIdx.x & 31, ty = threadIdx.x >> 5;
#pragma unroll
  for (int i = 0; i < 32; i += 8)
    tile[ty + i][tx] = in[(long long)(by + ty + i) * C + bx + tx];
  __syncthreads();
#pragma unroll
  for (int i = 0; i < 32; i += 8)
    out[(long long)(bx + ty + i) * R + by + tx] = __float2bfloat16(tile[tx][ty + i]);
}

__global__ void transpose_bf16_b(const bf16* __restrict__ in, bf16* __restrict__ out,
                                 int ld_in, int ld_out, long long sIn, long long sOut) {
  __shared__ bf16 tile[32][33];
  const bf16* ip = in + blockIdx.z * sIn;
  bf16* op = out + blockIdx.z * sOut;
  const int bx = blockIdx.x * 32;
  const int by = blockIdx.y * 32;
  const int tx = threadIdx.x & 31, ty = threadIdx.x >> 5;
#pragma unroll
  for (int i = 0; i < 32; i += 8)
    tile[ty + i][tx] = ip[(long long)(by + ty + i) * ld_in + bx + tx];
  __syncthreads();
#pragma unroll
  for (int i = 0; i < 32; i += 8)
    op[(long long)(bx + ty + i) * ld_out + by + tx] = tile[tx][ty + i];
}

__global__ void concat_bias(const float* __restrict__ a, const float* __restrict__ b,
                            float* __restrict__ out) {
  int i = blockIdx.x * 256 + threadIdx.x;
  out[i] = (i < 1024) ? a[i] : b[i - 1024];
}

// ---------------------------------------------------------------------------
__global__ void softmax_mask(bf16* __restrict__ S, const int* __restrict__ mask) {
  const int row = blockIdx.x;
  const int b = row >> 10;
  bf16* s = S + (long long)row * 2048;
  const int* mk = mask + b * 2048;
  const int t = threadIdx.x;
  const int lane = t & 63, wid = t >> 6;

  s16x8 xv = reinterpret_cast<const s16x8*>(s)[t];
  int4 m0 = reinterpret_cast<const int4*>(mk)[t * 2];
  int4 m1 = reinterpret_cast<const int4*>(mk)[t * 2 + 1];

  union { s16x8 v; bf16 h[8]; } u;
  u.v = xv;
  float v[8];
  const int mm[8] = {m0.x, m0.y, m0.z, m0.w, m1.x, m1.y, m1.z, m1.w};
#pragma unroll
  for (int j = 0; j < 8; ++j) v[j] = mm[j] ? __bfloat162float(u.h[j]) : -INFINITY;

  float mx = v[0];
#pragma unroll
  for (int j = 1; j < 8; ++j) mx = fmaxf(mx, v[j]);
  for (int off = 32; off; off >>= 1) mx = fmaxf(mx, __shfl_xor(mx, off, 64));
  __shared__ float redm[4];
  if (lane == 0) redm[wid] = mx;
  __syncthreads();
  mx = fmaxf(fmaxf(redm[0], redm[1]), fmaxf(redm[2], redm[3]));

  float e[8], sum = 0.f;
#pragma unroll
  for (int j = 0; j < 8; ++j) { e[j] = __expf(v[j] - mx); sum += e[j]; }
  for (int off = 32; off; off >>= 1) sum += __shfl_xor(sum, off, 64);
  __shared__ float reds[4];
  if (lane == 0) reds[wid] = sum;
  __syncthreads();
  sum = reds[0] + reds[1] + reds[2] + reds[3];
  const float inv = 1.0f / sum;

  union { bf16 h[8]; s16x8 v; } o;
#pragma unroll
  for (int j = 0; j < 8; ++j) o.h[j] = __float2bfloat16(e[j] * inv);
  reinterpret_cast<s16x8*>(s)[t] = o.v;
}

// ---------------------------------------------------------------------------
extern "C" void kernel_launch(void* const* d_in, const int* in_sizes, int n_in,
                              void* d_out, int out_size, void* d_ws, size_t ws_size,
                              hipStream_t stream) {
  const float* query = (const float*)d_in[0];      // [8,1024,1024]
  const float* key_value = (const float*)d_in[1];  // [8,2048,1024]
  const int* key_mask = (const int*)d_in[2];       // [8,2048]
  const float* Wq = (const float*)d_in[3];
  const float* bq = (const float*)d_in[4];
  const float* Wk = (const float*)d_in[5];
  const float* bk = (const float*)d_in[6];
  const float* Wv = (const float*)d_in[7];
  const float* bv = (const float*)d_in[8];
  const float* Wo = (const float*)d_in[9];
  const float* bo = (const float*)d_in[10];
  float* out = (float*)d_out;

  char* ws = (char*)d_ws;
  size_t off = 0;
  auto alloc = [&](size_t bytes) {
    char* p = ws + off;
    off += (bytes + 255) & ~(size_t)255;
    return p;
  };
  bf16* qb   = (bf16*)alloc(8192ull * 1024 * 2);
  bf16* kvb  = (bf16*)alloc(16384ull * 1024 * 2);
  bf16* WqT  = (bf16*)alloc(1024ull * 1024 * 2);
  bf16* WkvT = (bf16*)alloc(2048ull * 1024 * 2);
  bf16* WoT  = (bf16*)alloc(1024ull * 1024 * 2);
  float* bkv = (float*)alloc(2048 * 4);
  bf16* Qb   = (bf16*)alloc(8192ull * 1024 * 2);
  bf16* KVb  = (bf16*)alloc(16384ull * 2048 * 2);
  bf16* S    = (bf16*)alloc(8ull * 1024 * 2048 * 2);
  bf16* VT = kvb;  // alias: kv bf16 dead after KV projection
  bf16* Cb = Qb;   // alias: Qb dead after scores GEMM

  // 1. conversions / weight prep
  cvt_f32_bf16<<<8192, 256, 0, stream>>>(query, qb, 8192ll * 1024 / 4);
  cvt_f32_bf16<<<16384, 256, 0, stream>>>(key_value, kvb, 16384ll * 1024 / 4);
  transpose_f32_to_bf16<<<dim3(32, 32), 256, 0, stream>>>(Wq, WqT, 1024, 1024);
  transpose_f32_to_bf16<<<dim3(32, 32), 256, 0, stream>>>(Wk, WkvT, 1024, 1024);
  transpose_f32_to_bf16<<<dim3(32, 32), 256, 0, stream>>>(Wv, WkvT + 1024ll * 1024, 1024, 1024);
  transpose_f32_to_bf16<<<dim3(32, 32), 256, 0, stream>>>(Wo, WoT, 1024, 1024);
  concat_bias<<<8, 256, 0, stream>>>(bk, bv, bkv);

  // 2. Q projection: [8192,1024] -> Qb   (256x128 tiles, 256 blocks)
  gemm256<bf16, true, 2, 128><<<256, 512, 0, stream>>>(
      qb, WqT, Qb, bq, 1.f, 1024, 1024, 1024, 1024, 8, 0, 0, 0);

  // 3. fused K|V projection -> KVb [16384,2048]  (256x256, 512 blocks)
  gemm256<bf16, true, 2, 256><<<512, 512, 0, stream>>>(
      kvb, WkvT, KVb, bkv, 1.f, 1024, 1024, 1024, 2048, 8, 0, 0, 0);

  // 4. V^T per batch
  transpose_bf16_b<<<dim3(32, 64, 8), 256, 0, stream>>>(
      KVb + 1024, VT, 2048, 2048, 2048ll * 2048, 1024ll * 2048);

  // 5. scores: S = (Q @ K^T)/32, bf16  (256x256, 256 blocks, batch->XCD)
  gemm256<bf16, false, 1, 256><<<256, 512, 0, stream>>>(
      Qb, KVb, S, nullptr, 0.03125f, 1024, 1024, 2048, 2048, 8,
      1024ll * 1024, 2048ll * 2048, 1024ll * 2048);

  // 6. masked softmax in-place
  softmax_mask<<<8192, 256, 0, stream>>>(S, key_mask);

  // 7. context = P @ V  (256x128, 256 blocks, batch->XCD)
  gemm256<bf16, false, 1, 128><<<256, 512, 0, stream>>>(
      S, VT, Cb, nullptr, 1.f, 2048, 2048, 2048, 1024, 8,
      1024ll * 2048, 1024ll * 2048, 1024ll * 1024);

  // 8. out = Cb @ Wo + bo  (256x128, 256 blocks)
  gemm256<float, true, 2, 128><<<256, 512, 0, stream>>>(
      Cb, WoT, out, bo, 1.f, 1024, 1024, 1024, 1024, 8, 0, 0, 0);
}

// Round 5
// 283.417 us; speedup vs baseline: 1.3155x; 1.1581x over previous
//
#include <hip/hip_runtime.h>
#include <hip/hip_bf16.h>

typedef __hip_bfloat16 bf16;
typedef float f32x4 __attribute__((ext_vector_type(4)));
typedef short s16x8 __attribute__((ext_vector_type(8)));

// ---------------------------------------------------------------------------
__device__ __forceinline__ void async_load16(const void* g, void* lds) {
  __builtin_amdgcn_global_load_lds(
      (const __attribute__((address_space(1))) void*)g,
      (__attribute__((address_space(3))) void*)lds, 16, 0, 0);
}

__device__ __forceinline__ void store_out(float* p, float v) { *p = v; }
__device__ __forceinline__ void store_out(bf16* p, float v) { *p = __float2bfloat16(v); }

// ---------------------------------------------------------------------------
// C[M,N] = scale*(A[M,K] @ BT[N,K]^T) + bias. bf16 in, f32 acc.
// 128x128 tile, BK=32, double-buffered LDS with next-tile prefetch,
// 4 waves (2x2 of 64x64), 16x16x32 bf16 MFMA.  [r2-proven structure, 784 TF]
// BIASMODE: 0 = none, 1 = per-column bias, 2 = per-row bias.
// SWZ=1: batched launch, id&7 = batch (pins batch->XCD).
// SWZ=2: non-batched, chunked XCD swizzle (grid must be %8==0).
template <typename OutT, int BIASMODE, int SWZ>
__global__ void gemm_bt(const bf16* __restrict__ Ag, const bf16* __restrict__ Bg,
                        OutT* Cg, const float* __restrict__ biasp, float scale,
                        int K, int lda, int ldb, int ldc, int ntx,
                        long long sA, long long sB, long long sC) {
  __shared__ bf16 As[2][128 * 32];
  __shared__ bf16 Bs[2][128 * 32];

  const int id = blockIdx.x;
  int bz = 0, tile;
  if (SWZ == 1) { bz = id & 7; tile = id >> 3; }
  else { const int q = gridDim.x >> 3; tile = (id & 7) * q + (id >> 3); }
  const int tn = tile % ntx, tm = tile / ntx;

  const bf16* A = Ag + bz * sA;
  const bf16* BT = Bg + bz * sB;
  OutT* C = Cg + bz * sC;

  const int t = threadIdx.x;
  const int lane = t & 63;
  const int wid = t >> 6;
  const int wr = wid >> 1, wc = wid & 1;
  const int lo = lane & 15, hi = lane >> 4;

  const int arow0 = tm * 128, brow0 = tn * 128;

  // staging: 2 chunks of 16B per thread per operand (tile row = 64B)
  const int idx0 = t, idx1 = 256 + t;
  const int r0 = idx0 >> 2, c0 = (idx0 & 3) * 8;
  const int r1 = idx1 >> 2, c1 = (idx1 & 3) * 8;
  const bf16* a0 = A + (long long)(arow0 + r0) * lda + c0;
  const bf16* a1 = A + (long long)(arow0 + r1) * lda + c1;
  const bf16* b0 = BT + (long long)(brow0 + r0) * ldb + c0;
  const bf16* b1 = BT + (long long)(brow0 + r1) * ldb + c1;

  f32x4 acc[4][4] = {};
  const int nt = K >> 5;

  // prologue: stage tile 0
  async_load16(a0, &As[0][idx0 * 8]);
  async_load16(a1, &As[0][idx1 * 8]);
  async_load16(b0, &Bs[0][idx0 * 8]);
  async_load16(b1, &Bs[0][idx1 * 8]);
  __syncthreads();

  int cur = 0;
  for (int kt = 0; kt < nt; ++kt) {
    const int nxt = cur ^ 1;
    if (kt + 1 < nt) {  // issue next tile's loads BEFORE computing current
      const int k0 = (kt + 1) << 5;
      async_load16(a0 + k0, &As[nxt][idx0 * 8]);
      async_load16(a1 + k0, &As[nxt][idx1 * 8]);
      async_load16(b0 + k0, &Bs[nxt][idx0 * 8]);
      async_load16(b1 + k0, &Bs[nxt][idx1 * 8]);
    }
    s16x8 a[4], b[4];
#pragma unroll
    for (int m = 0; m < 4; ++m)
      a[m] = *(const s16x8*)&As[cur][(wr * 64 + m * 16 + lo) * 32 + hi * 8];
#pragma unroll
    for (int n = 0; n < 4; ++n)
      b[n] = *(const s16x8*)&Bs[cur][(wc * 64 + n * 16 + lo) * 32 + hi * 8];
#pragma unroll
    for (int m = 0; m < 4; ++m)
#pragma unroll
      for (int n = 0; n < 4; ++n)
        acc[m][n] = __builtin_amdgcn_mfma_f32_16x16x32_bf16(a[m], b[n], acc[m][n], 0, 0, 0);
    __syncthreads();
    cur = nxt;
  }

  // C/D layout: col = lane&15, row = (lane>>4)*4 + reg
  float bcol[4] = {0.f, 0.f, 0.f, 0.f};
  if (BIASMODE == 1) {
#pragma unroll
    for (int n = 0; n < 4; ++n)
      bcol[n] = biasp[brow0 + wc * 64 + n * 16 + lo];
  }
#pragma unroll
  for (int m = 0; m < 4; ++m) {
    const int row = arow0 + wr * 64 + m * 16 + hi * 4;
    float br[4] = {0.f, 0.f, 0.f, 0.f};
    if (BIASMODE == 2) {
      float4 t4 = *(const float4*)&biasp[row];
      br[0] = t4.x; br[1] = t4.y; br[2] = t4.z; br[3] = t4.w;
    }
#pragma unroll
    for (int n = 0; n < 4; ++n) {
      const int col = brow0 + wc * 64 + n * 16 + lo;
#pragma unroll
      for (int j = 0; j < 4; ++j)
        store_out(&C[(long long)(row + j) * ldc + col],
                  acc[m][n][j] * scale + bcol[n] + br[j]);
    }
  }
}

// ---------------------------------------------------------------------------
__global__ void cvt_f32_bf16(const float* __restrict__ in, bf16* __restrict__ out,
                             long long n4) {
  long long i = (long long)blockIdx.x * 256 + threadIdx.x;
  if (i >= n4) return;
  float4 v = reinterpret_cast<const float4*>(in)[i];
  union { bf16 h[4]; unsigned long long u; } cv;
  cv.h[0] = __float2bfloat16(v.x);
  cv.h[1] = __float2bfloat16(v.y);
  cv.h[2] = __float2bfloat16(v.z);
  cv.h[3] = __float2bfloat16(v.w);
  reinterpret_cast<unsigned long long*>(out)[i] = cv.u;
}

// four 1024x1024 f32 -> bf16 transposes in one launch (blockIdx.z selects)
__global__ void transpose4_f32_to_bf16(const float* __restrict__ W0, const float* __restrict__ W1,
                                       const float* __restrict__ W2, const float* __restrict__ W3,
                                       bf16* __restrict__ O0, bf16* __restrict__ O1,
                                       bf16* __restrict__ O2, bf16* __restrict__ O3) {
  const float* in; bf16* out;
  switch (blockIdx.z) {
    case 0: in = W0; out = O0; break;
    case 1: in = W1; out = O1; break;
    case 2: in = W2; out = O2; break;
    default: in = W3; out = O3; break;
  }
  __shared__ float tile[32][33];
  const int bx = blockIdx.x * 32, by = blockIdx.y * 32;
  const int tx = threadIdx.x & 31, ty = threadIdx.x >> 5;
#pragma unroll
  for (int i = 0; i < 32; i += 8)
    tile[ty + i][tx] = in[(long long)(by + ty + i) * 1024 + bx + tx];
  __syncthreads();
#pragma unroll
  for (int i = 0; i < 32; i += 8)
    out[(long long)(bx + ty + i) * 1024 + by + tx] = __float2bfloat16(tile[tx][ty + i]);
}

// ---------------------------------------------------------------------------
// masked softmax over rows of S (bf16, already scaled), IN-PLACE. one block/row.
__global__ void softmax_mask(bf16* __restrict__ S, const int* __restrict__ mask) {
  const int row = blockIdx.x;  // b*1024 + q
  const int b = row >> 10;
  bf16* s = S + (long long)row * 2048;
  const int* mk = mask + b * 2048;
  const int t = threadIdx.x;
  const int lane = t & 63, wid = t >> 6;

  s16x8 xv = reinterpret_cast<const s16x8*>(s)[t];
  int4 m0 = reinterpret_cast<const int4*>(mk)[t * 2];
  int4 m1 = reinterpret_cast<const int4*>(mk)[t * 2 + 1];

  union { s16x8 v; bf16 h[8]; } u;
  u.v = xv;
  float v[8];
  const int mm[8] = {m0.x, m0.y, m0.z, m0.w, m1.x, m1.y, m1.z, m1.w};
#pragma unroll
  for (int j = 0; j < 8; ++j) v[j] = mm[j] ? __bfloat162float(u.h[j]) : -INFINITY;

  float mx = v[0];
#pragma unroll
  for (int j = 1; j < 8; ++j) mx = fmaxf(mx, v[j]);
  for (int off = 32; off; off >>= 1) mx = fmaxf(mx, __shfl_xor(mx, off, 64));
  __shared__ float redm[4];
  if (lane == 0) redm[wid] = mx;
  __syncthreads();
  mx = fmaxf(fmaxf(redm[0], redm[1]), fmaxf(redm[2], redm[3]));

  float e[8], sum = 0.f;
#pragma unroll
  for (int j = 0; j < 8; ++j) { e[j] = __expf(v[j] - mx); sum += e[j]; }
  for (int off = 32; off; off >>= 1) sum += __shfl_xor(sum, off, 64);
  __shared__ float reds[4];
  if (lane == 0) reds[wid] = sum;
  __syncthreads();
  sum = reds[0] + reds[1] + reds[2] + reds[3];
  const float inv = 1.0f / sum;

  union { bf16 h[8]; s16x8 v; } o;
#pragma unroll
  for (int j = 0; j < 8; ++j) o.h[j] = __float2bfloat16(e[j] * inv);
  reinterpret_cast<s16x8*>(s)[t] = o.v;
}

// ---------------------------------------------------------------------------
extern "C" void kernel_launch(void* const* d_in, const int* in_sizes, int n_in,
                              void* d_out, int out_size, void* d_ws, size_t ws_size,
                              hipStream_t stream) {
  const float* query = (const float*)d_in[0];      // [8,1024,1024]
  const float* key_value = (const float*)d_in[1];  // [8,2048,1024]
  const int* key_mask = (const int*)d_in[2];       // [8,2048]
  const float* Wq = (const float*)d_in[3];
  const float* bq = (const float*)d_in[4];
  const float* Wk = (const float*)d_in[5];
  const float* bk = (const float*)d_in[6];
  const float* Wv = (const float*)d_in[7];
  const float* bv = (const float*)d_in[8];
  const float* Wo = (const float*)d_in[9];
  const float* bo = (const float*)d_in[10];
  float* out = (float*)d_out;

  char* ws = (char*)d_ws;
  size_t off = 0;
  auto alloc = [&](size_t bytes) {
    char* p = ws + off;
    off += (bytes + 255) & ~(size_t)255;
    return p;
  };
  bf16* qb  = (bf16*)alloc(8192ull * 1024 * 2);     // query bf16
  bf16* kvb = (bf16*)alloc(16384ull * 1024 * 2);    // key_value bf16
  bf16* WqT = (bf16*)alloc(1024ull * 1024 * 2);
  bf16* WkT = (bf16*)alloc(1024ull * 1024 * 2);
  bf16* WvT = (bf16*)alloc(1024ull * 1024 * 2);
  bf16* WoT = (bf16*)alloc(1024ull * 1024 * 2);
  bf16* Qb  = (bf16*)alloc(8192ull * 1024 * 2);     // later: Cb
  bf16* Kb  = (bf16*)alloc(16384ull * 1024 * 2);    // K proj [8][2048][1024]
  bf16* VT  = (bf16*)alloc(8192ull * 2048 * 2);     // V^T [8][1024][2048]
  bf16* S   = (bf16*)alloc(8ull * 1024 * 2048 * 2); // scores, softmax in-place
  bf16* Cb = Qb;  // alias: Qb dead after scores GEMM

  // 1. conversions / weight prep (one batched transpose launch)
  cvt_f32_bf16<<<8192, 256, 0, stream>>>(query, qb, 8192ll * 1024 / 4);
  cvt_f32_bf16<<<16384, 256, 0, stream>>>(key_value, kvb, 16384ll * 1024 / 4);
  transpose4_f32_to_bf16<<<dim3(32, 32, 4), 256, 0, stream>>>(
      Wq, Wk, Wv, Wo, WqT, WkT, WvT, WoT);

  // 2. Q projection: [8192,1024] @ Wq + bq -> Qb
  gemm_bt<bf16, 1, 2><<<512, 256, 0, stream>>>(
      qb, WqT, Qb, bq, 1.f, 1024, 1024, 1024, 1024, 8, 0, 0, 0);

  // 3. K projection: [16384,1024] @ Wk + bk -> Kb
  gemm_bt<bf16, 1, 2><<<1024, 256, 0, stream>>>(
      kvb, WkT, Kb, bk, 1.f, 1024, 1024, 1024, 1024, 8, 0, 0, 0);

  // 4. V^T projection (direct, no transpose pass):
  //    VT[b][h][s] = sum_d WvT[h][d] * kv[b][s][d] + bv[h]   (row bias)
  gemm_bt<bf16, 2, 1><<<1024, 256, 0, stream>>>(
      WvT, kvb, VT, bv, 1.f, 1024, 1024, 1024, 2048, 16,
      0, 2048ll * 1024, 1024ll * 2048);

  // 5. scores: S = (Q @ K^T)/32, bf16, batch->XCD pinned
  gemm_bt<bf16, 0, 1><<<1024, 256, 0, stream>>>(
      Qb, Kb, S, nullptr, 0.03125f, 1024, 1024, 1024, 2048, 16,
      1024ll * 1024, 2048ll * 1024, 1024ll * 2048);

  // 6. masked softmax in-place -> P
  softmax_mask<<<8192, 256, 0, stream>>>(S, key_mask);

  // 7. context = P @ V (BT = VT[h][s]), batch->XCD pinned
  gemm_bt<bf16, 0, 1><<<512, 256, 0, stream>>>(
      S, VT, Cb, nullptr, 1.f, 2048, 2048, 2048, 1024, 8,
      1024ll * 2048, 1024ll * 2048, 1024ll * 1024);

  // 8. out = Cb @ Wo + bo (f32)
  gemm_bt<float, 1, 2><<<512, 256, 0, stream>>>(
      Cb, WoT, out, bo, 1.f, 1024, 1024, 1024, 1024, 8, 0, 0, 0);
}